// Round 4
// baseline (317.108 us; speedup 1.0000x reference)
//
#include <hip/hip_runtime.h>

typedef __attribute__((ext_vector_type(2))) float f32x2;
typedef __attribute__((ext_vector_type(4))) float f32x4;
typedef __attribute__((ext_vector_type(8))) short s16x8;
typedef __attribute__((ext_vector_type(2))) unsigned int u32x2;
typedef __attribute__((ext_vector_type(4))) unsigned int u32x4;

#define BN 4
#define TN 4096
#define CN 120
#define HN 64

// RNE float->bf16 (finite inputs only)
__device__ __forceinline__ unsigned short f2bf(float f) {
  unsigned int u = __float_as_uint(f);
  unsigned int r = (u + 0x7fffu + ((u >> 16) & 1u)) >> 16;
  return (unsigned short)r;
}
__device__ __forceinline__ float bf2f(unsigned short h) {
  return __uint_as_float((unsigned int)h << 16);
}
__device__ __forceinline__ float fast_exp2(float x) {
#if __has_builtin(__builtin_amdgcn_exp2f)
  return __builtin_amdgcn_exp2f(x);
#else
  return exp2f(x);
#endif
}

// ---------------------------------------------------------------------------
// Workspace layouts (validated r10): K and V stored PRE-PERMUTED into MFMA
// fragment order so every in-loop global load in attn is base + lane*16.
//   Kf[b][kt]   : kt = key/16, 2KB tile. chunk0 byte L*16 = K[b][kt*16 +
//                 (L&15)][h=(L>>4)*8..+8); chunk1 (+1024B) same rows, h+32.
//   Qg[b*T+t][64] rows (bf16, pre-scaled by log2(e)/sqrt(120)).
//   Vf[b][kb32][ht]: 1KB: byte L*16 = V[b][h=ht*16+(L&15)][kb32*32 +
//                 (L>>4)*8..+8).
// ---------------------------------------------------------------------------

// ---------------------------------------------------------------------------
// Kernel 1: projections — unchanged (est ~5us, not the bottleneck).
// ---------------------------------------------------------------------------
__global__ __launch_bounds__(256, 3) void proj_kernel(
    const float* __restrict__ x, const float* __restrict__ Wk,
    const float* __restrict__ Wq, const float* __restrict__ Wv,
    unsigned short* __restrict__ Kf, unsigned short* __restrict__ Qg,
    unsigned short* __restrict__ Vf) {
  __shared__ struct {
    unsigned short xh[64][136];  // bf16 hi, pitch 136 shorts       17408 B
    unsigned short xl[64][136];  // bf16 lo residual                17408 B
    unsigned short vt[64][72];   // transpose buffer (pitch 72)      9216 B
  } sm;
  const int tid = threadIdx.x;
  const int mat = blockIdx.x >> 8;  // 0=K 1=Q 2=V
  const int rb = blockIdx.x & 255;
  const int row0 = rb * 64;
  const int wave = tid >> 6, lane = tid & 63;
  const int l15 = lane & 15, quad = lane >> 4;
  const int b = row0 >> 12, key0 = row0 & (TN - 1);

  // ---- W B-frags (hi/lo) for this wave's h-tile ----
  const float* Ws = (mat == 0) ? Wk : (mat == 1) ? Wq : Wv;
  const float wsc = (mat == 1) ? 0.13169944f : 1.0f;  // log2(e)/sqrt(120)
  s16x8 wh[4], wl[4];
#pragma unroll
  for (int kc = 0; kc < 4; ++kc) {
#pragma unroll
    for (int j = 0; j < 8; ++j) {
      const int c = kc * 32 + quad * 8 + j;
      const float w = (c < CN) ? Ws[c * HN + wave * 16 + l15] * wsc : 0.f;
      const unsigned short h16 = f2bf(w);
      wh[kc][j] = (short)h16;
      wl[kc][j] = (short)f2bf(w - bf2f(h16));
    }
  }

  // ---- stage x: global f32x4 coalesced, split hi/lo during the copy ----
  for (int n = tid; n < 64 * 30; n += 256) {
    const int row = n / 30, c4 = n - row * 30;
    const f32x4 xv = *(const f32x4*)&x[(size_t)(row0 + row) * CN + c4 * 4];
    u32x2 hp, lp;
#pragma unroll
    for (int e = 0; e < 2; ++e) {
      const unsigned short h0 = f2bf(xv[2 * e]);
      const unsigned short h1 = f2bf(xv[2 * e + 1]);
      hp[e] = (unsigned int)h0 | ((unsigned int)h1 << 16);
      lp[e] = (unsigned int)f2bf(xv[2 * e] - bf2f(h0)) |
              ((unsigned int)f2bf(xv[2 * e + 1] - bf2f(h1)) << 16);
    }
    *(u32x2*)&sm.xh[row][c4 * 4] = hp;
    *(u32x2*)&sm.xl[row][c4 * 4] = lp;
  }
  if (tid < 64) {  // zero-pad c 120..127
    const u32x4 z = {0u, 0u, 0u, 0u};
    *(u32x4*)&sm.xh[tid][120] = z;
    *(u32x4*)&sm.xl[tid][120] = z;
  }
  __syncthreads();

  // ---- MFMA main: 4 m-tiles x 4 k-chunks x 3 split terms ----
  f32x4 acc[4];
#pragma unroll
  for (int mt = 0; mt < 4; ++mt) acc[mt] = 0.f;
#pragma unroll
  for (int mt = 0; mt < 4; ++mt) {
#pragma unroll
    for (int kc = 0; kc < 4; ++kc) {
      const s16x8 ah = *(const s16x8*)&sm.xh[mt * 16 + l15][kc * 32 + quad * 8];
      const s16x8 al = *(const s16x8*)&sm.xl[mt * 16 + l15][kc * 32 + quad * 8];
      acc[mt] = __builtin_amdgcn_mfma_f32_16x16x32_bf16(al, wh[kc], acc[mt], 0, 0, 0);
      acc[mt] = __builtin_amdgcn_mfma_f32_16x16x32_bf16(ah, wl[kc], acc[mt], 0, 0, 0);
      acc[mt] = __builtin_amdgcn_mfma_f32_16x16x32_bf16(ah, wh[kc], acc[mt], 0, 0, 0);
    }
  }

  // ---- epilogue: C-layout -> vt -> global ----
  if (mat < 2) {
    // rows in vt[row][h]
#pragma unroll
    for (int mt = 0; mt < 4; ++mt)
#pragma unroll
      for (int r = 0; r < 4; ++r)
        sm.vt[mt * 16 + quad * 4 + r][wave * 16 + l15] = f2bf(acc[mt][r]);
    __syncthreads();
    if (mat == 1) {
      // Qg rows — each thread owns a 32B quarter-row -> TWO u32x4
      const int row = tid >> 2, seg = tid & 3;
      const u32x4 d0 = *(const u32x4*)&sm.vt[row][seg * 16];
      const u32x4 d1 = *(const u32x4*)&sm.vt[row][seg * 16 + 8];
      unsigned short* qp = &Qg[(size_t)(row0 + row) * HN + seg * 16];
      *(u32x4*)qp = d0;
      *(u32x4*)(qp + 8) = d1;
    } else {
      // Kf frag-ordered tiles (512 chunks, full coverage)
#pragma unroll
      for (int i = 0; i < 2; ++i) {
        const int c = tid + i * 256;  // 512 chunks: 4 kt x 2 ch x 64 L
        const int ktl = c >> 7, ch = (c >> 6) & 1, L = c & 63;
        const u32x4 d =
            *(const u32x4*)&sm.vt[ktl * 16 + (L & 15)][(L >> 4) * 8 + ch * 32];
        *(u32x4*)((unsigned char*)Kf +
                  (((size_t)b * 256 + (key0 >> 4) + ktl) * 128 + ch * 64 + L) *
                      16) = d;
      }
    }
  } else {
    // V transposed in vt[h][row]
#pragma unroll
    for (int mt = 0; mt < 4; ++mt)
#pragma unroll
      for (int r = 0; r < 4; ++r)
        sm.vt[wave * 16 + l15][mt * 16 + quad * 4 + r] = f2bf(acc[mt][r]);
    __syncthreads();
#pragma unroll
    for (int i = 0; i < 2; ++i) {
      const int c = tid + i * 256;  // 512 chunks: 2 kb32 x 4 ht x 64 L
      const int kbl = c >> 8, ht = (c >> 6) & 3, L = c & 63;
      const u32x4 d =
          *(const u32x4*)&sm.vt[ht * 16 + (L & 15)][kbl * 32 + (L >> 4) * 8];
      *(u32x4*)((unsigned char*)Vf +
                (((size_t)b * 128 + (key0 >> 5) + kbl) * 4 + ht) * 1024 +
                L * 16) = d;
    }
  }
}

// ---------------------------------------------------------------------------
// Kernel 2: attention v5 — OCCUPANCY x2 via 16-wave blocks. Post-mortem r3:
// fixed non-attn floor ~63us (one 41us poison + proj + reset dispatches);
// v1 attn ~36us vs per-SIMD pipe sums ~12us (MFMA 8.3 + VALU 1.7 + TRANS
// 1.7) and R2's OccupancyPercent=40% exposed the gap: grid 512 x 8 waves =
// 2 blocks/CU = only 4 waves/SIMD -> latency-bound. Fix with ZERO register
// cost (r2 lesson: 64-VGPR budget is sacred): same 32 queries/block, but
// keys split 16 ways -> 1024-thread blocks, 256 keys/wave, 4 iterations.
// Grid stays 512 = 2 blocks/CU, now 32 waves/CU = 8 waves/SIMD (2x TLP).
// LDS p[16][2][16][72] = 73728B dynamic (2 blocks x 73728 = 147KB <= 160KB);
// epilogue combines 16 waves in-LDS (ob[16][64][17]+lb[16][16] = 70656B).
// All setprio REMOVED (r3 suspect: 16 toggles/iter in PV = the measured-
// negative regime). Inner math identical to v4 (strictly fewer VALU ops
// than v1, bit-identical P values).
// ---------------------------------------------------------------------------
__global__ __launch_bounds__(1024, 8) void attn_kernel(
    const unsigned short* __restrict__ Qg, const unsigned short* __restrict__ Kf,
    const unsigned short* __restrict__ Vf, float* __restrict__ out) {
  extern __shared__ unsigned char smraw[];  // 73728 B
  const int bid = blockIdx.x;                      // [0,512)
  const int xslot = bid & 7;                       // XCD-aware swizzle
  const int b = xslot >> 1;                        // batch -> XCD pair
  const int qt5 = (bid >> 3) | ((xslot & 1) << 6); // [0,128)
  const int qbase = qt5 * 32;
  const int tid = threadIdx.x;
  const int wave = tid >> 6, lane = tid & 63;      // wave in [0,16)
  const int l15 = lane & 15, quad = lane >> 4;

  // Q B-operand frags for both q-tiles: B[k=h][n=q]: q=l15, h=quad*8+j (+32)
  s16x8 qf[2][2];
#pragma unroll
  for (int qt = 0; qt < 2; ++qt) {
    const unsigned short* qrow =
        Qg + (size_t)(b * TN + qbase + qt * 16 + l15) * HN + quad * 8;
    qf[qt][0] = *(const s16x8*)qrow;
    qf[qt][1] = *(const s16x8*)(qrow + 32);
  }

  const unsigned char* Kfb = (const unsigned char*)Kf + (size_t)b * 524288;
  const unsigned char* Vfb = (const unsigned char*)Vf + (size_t)b * 524288;
  // P slab per (wave,qt): 16 rows x 72 shorts = 2304 B
  char* pw[2];
#pragma unroll
  for (int qt = 0; qt < 2; ++qt)
    pw[qt] = (char*)smraw + (wave * 2 + qt) * 2304 + l15 * 144;

  f32x4 o[2][4];
#pragma unroll
  for (int qt = 0; qt < 2; ++qt)
#pragma unroll
    for (int t = 0; t < 4; ++t) o[qt][t] = 0.f;
  f32x2 la2[2];
  la2[0] = 0.f;
  la2[1] = 0.f;

  const int kb0 = wave * 256;  // 16-way key split, 256 keys/wave
#pragma unroll 1
  for (int it = 0; it < 4; ++it) {
    const int kb = kb0 + it * 64;
    // ---- per 16-key tile t: S MFMAs then IMMEDIATE exp/pack (s dies) ----
#pragma unroll
    for (int t = 0; t < 4; ++t) {
      const unsigned char* ktp =
          Kfb + (size_t)((kb >> 4) + t) * 2048 + lane * 16;
      const s16x8 a0 = *(const s16x8*)ktp;
      const s16x8 a1 = *(const s16x8*)(ktp + 1024);
      f32x4 s0 = 0.f, s1 = 0.f;
      s0 = __builtin_amdgcn_mfma_f32_16x16x32_bf16(a0, qf[0][0], s0, 0, 0, 0);
      s0 = __builtin_amdgcn_mfma_f32_16x16x32_bf16(a1, qf[0][1], s0, 0, 0, 0);
      s1 = __builtin_amdgcn_mfma_f32_16x16x32_bf16(a0, qf[1][0], s1, 0, 0, 0);
      s1 = __builtin_amdgcn_mfma_f32_16x16x32_bf16(a1, qf[1][1], s1, 0, 0, 0);
      // exp2, truncate to bf16, l from truncated values, store P^T.
      // C/D layout: q=l15(col), key = 16t + quad*4 + reg.
#pragma unroll
      for (int qt = 0; qt < 2; ++qt) {
        const f32x4 s = qt ? s1 : s0;
        const unsigned int u0 = __float_as_uint(fast_exp2(s[0]));
        const unsigned int u1 = __float_as_uint(fast_exp2(s[1]));
        const unsigned int u2 = __float_as_uint(fast_exp2(s[2]));
        const unsigned int u3 = __float_as_uint(fast_exp2(s[3]));
        const unsigned int m0 = u0 & 0xffff0000u, m1 = u1 & 0xffff0000u;
        const unsigned int m2 = u2 & 0xffff0000u, m3 = u3 & 0xffff0000u;
        f32x2 pa, pb;
        pa.x = __uint_as_float(m0);
        pa.y = __uint_as_float(m1);
        pb.x = __uint_as_float(m2);
        pb.y = __uint_as_float(m3);
        la2[qt] += pa + pb;  // packed accumulate (v_pk_add_f32)
        u32x2 w;
        w.x = __builtin_amdgcn_perm(u1, u0, 0x07060302u);  // (u0>>16)|m1
        w.y = __builtin_amdgcn_perm(u3, u2, 0x07060302u);  // (u2>>16)|m3
        *(u32x2*)(pw[qt] + t * 32 + quad * 8) = w;  // keys 16t+quad*4..+3
      }
    }
    // ---- O^T += V * P^T (V frags reused 2x; same-wave LDS RAW) ----
#pragma unroll 1
    for (int kc = 0; kc < 2; ++kc) {
      const s16x8 pb0 = *(const s16x8*)(pw[0] + quad * 16 + kc * 64);
      const s16x8 pb1 = *(const s16x8*)(pw[1] + quad * 16 + kc * 64);
#pragma unroll
      for (int ht = 0; ht < 4; ++ht) {
        const unsigned char* vtp =
            Vfb + (size_t)((kb >> 5) + kc) * 4096 + ht * 1024 + lane * 16;
        const s16x8 va = *(const s16x8*)vtp;
        o[0][ht] = __builtin_amdgcn_mfma_f32_16x16x32_bf16(va, pb0, o[0][ht], 0, 0, 0);
        o[1][ht] = __builtin_amdgcn_mfma_f32_16x16x32_bf16(va, pb1, o[1][ht], 0, 0, 0);
      }
    }
  }
  // horizontal add of packed l, then reduce across quads (q=l15 fixed)
  float lacc[2];
#pragma unroll
  for (int qt = 0; qt < 2; ++qt) {
    lacc[qt] = la2[qt].x + la2[qt].y;
    lacc[qt] += __shfl_xor(lacc[qt], 16, 64);
    lacc[qt] += __shfl_xor(lacc[qt], 32, 64);
  }
  __syncthreads();  // all waves done with P slabs before LDS reuse
  // two-phase epilogue over 16 waves (literal qt keeps o in VGPRs)
  float* ob = (float*)smraw;                        // [16][64][17]  69632 B
  float* lb = (float*)(smraw + 16 * 64 * 17 * 4);   // [16][16]       1024 B
#pragma unroll
  for (int qt = 0; qt < 2; ++qt) {
    if (lane < 16) lb[wave * 16 + l15] = lacc[qt];
#pragma unroll
    for (int ht = 0; ht < 4; ++ht)
#pragma unroll
      for (int r = 0; r < 4; ++r)
        ob[(wave * 64 + ht * 16 + quad * 4 + r) * 17 + l15] = o[qt][ht][r];
    __syncthreads();
    const int h = tid & 63;
    const int wq = tid >> 6;  // 0..15 == query within tile
    float ssum = 0.f, ll = 0.f;
#pragma unroll
    for (int w = 0; w < 16; ++w) {
      ssum += ob[(w * 64 + h) * 17 + wq];
      ll += lb[w * 16 + wq];
    }
    out[(size_t)(b * TN + qbase + qt * 16 + wq) * HN + h] = ssum / ll;
    __syncthreads();  // phase qt's reads done before phase qt+1 overwrites
  }
}

extern "C" void kernel_launch(void* const* d_in, const int* in_sizes, int n_in,
                              void* d_out, int out_size, void* d_ws,
                              size_t ws_size, hipStream_t stream) {
  const float* x = (const float*)d_in[0];
  const float* Wk = (const float*)d_in[1];
  const float* Wq = (const float*)d_in[2];
  const float* Wv = (const float*)d_in[3];
  unsigned short* Kf = (unsigned short*)d_ws;             // [B][256] 2KB tiles
  unsigned short* Qg = Kf + (size_t)BN * TN * HN;         // [B*T][64] rows
  unsigned short* Vf = Qg + (size_t)BN * TN * HN;         // [B][128][4] 1KB
  float* out = (float*)d_out;
  static bool smset = false;
  if (!smset) {
    (void)hipFuncSetAttribute((const void*)attn_kernel,
                              hipFuncAttributeMaxDynamicSharedMemorySize,
                              73728);
    smset = true;
  }
  proj_kernel<<<768, 256, 0, stream>>>(x, Wk, Wq, Wv, Kf, Qg, Vf);
  attn_kernel<<<BN * TN / 32, 1024, 73728, stream>>>(Qg, Kf, Vf, out);
}

// Round 5
// 99.854 us; speedup vs baseline: 3.1757x; 3.1757x over previous
//
#include <hip/hip_runtime.h>

typedef __attribute__((ext_vector_type(2))) float f32x2;
typedef __attribute__((ext_vector_type(4))) float f32x4;
typedef __attribute__((ext_vector_type(8))) short s16x8;
typedef __attribute__((ext_vector_type(2))) unsigned int u32x2;
typedef __attribute__((ext_vector_type(4))) unsigned int u32x4;

#define BN 4
#define TN 4096
#define CN 120
#define HN 64

// RNE float->bf16 (finite inputs only)
__device__ __forceinline__ unsigned short f2bf(float f) {
  unsigned int u = __float_as_uint(f);
  unsigned int r = (u + 0x7fffu + ((u >> 16) & 1u)) >> 16;
  return (unsigned short)r;
}
__device__ __forceinline__ float bf2f(unsigned short h) {
  return __uint_as_float((unsigned int)h << 16);
}
__device__ __forceinline__ float fast_exp2(float x) {
#if __has_builtin(__builtin_amdgcn_exp2f)
  return __builtin_amdgcn_exp2f(x);
#else
  return exp2f(x);
#endif
}

// ---------------------------------------------------------------------------
// Workspace layouts (validated r10): K and V stored PRE-PERMUTED into MFMA
// fragment order so every in-loop global load in attn is base + lane*16.
//   Kf[b][kt]   : kt = key/16, 2KB tile. chunk0 byte L*16 = K[b][kt*16 +
//                 (L&15)][h=(L>>4)*8..+8); chunk1 (+1024B) same rows, h+32.
//   Qg[b*T+t][64] rows (bf16, pre-scaled by log2(e)/sqrt(120)).
//   Vf[b][kb32][ht]: 1KB: byte L*16 = V[b][h=ht*16+(L&15)][kb32*32 +
//                 (L>>4)*8..+8).
//
// SESSION LEDGER (rounds 1-4, all regressions — this file is the byte-exact
// revert to the verified 99.2us kernel):
//   r1  64q/wave, 2 blocks/CU:           +5.7us (occupancy loss > L2 gain)
//   r2  reg-pipelined prefetch:          +55us  (VGPR budget 128=64+64 split,
//                                               needed ~150 -> spill, 240MB scratch)
//   r3  no-fmin + pk-add + perm + setprio: +5us (setprio toggling suspect)
//   r4  16-wave blocks, launch_bounds(1024,8): +218us (budget 512/8=64 ->
//                                               32 arch VGPR -> total spill)
// Resource model learned: per-SIMD reg pool ~512/lane-slot; this kernel's
// working set (~64 arch + 32 acc) caps occupancy at 4 waves/SIMD — which
// the kernel below already achieves. Do not perturb its register schedule.
// ---------------------------------------------------------------------------

// ---------------------------------------------------------------------------
// Kernel 1: projections — MFMA engine. x,W split hi/lo bf16 (3 MFMA terms,
// rel err ~2^-17 << bf16 output rounding), Q scale folded into W pre-split,
// K=120 zero-padded to 128, grid 768 (one mat/block), 4 waves x 16-h tile.
// A-frag: m=l15, k=quad*8+j  |  B-frag: n=l15, k=quad*8+j  |
// C: col=l15(n), row=quad*4+reg(m)   [mappings attn-verified]
// ---------------------------------------------------------------------------
__global__ __launch_bounds__(256, 3) void proj_kernel(
    const float* __restrict__ x, const float* __restrict__ Wk,
    const float* __restrict__ Wq, const float* __restrict__ Wv,
    unsigned short* __restrict__ Kf, unsigned short* __restrict__ Qg,
    unsigned short* __restrict__ Vf) {
  __shared__ struct {
    unsigned short xh[64][136];  // bf16 hi, pitch 136 shorts       17408 B
    unsigned short xl[64][136];  // bf16 lo residual                17408 B
    unsigned short vt[64][72];   // transpose buffer (pitch 72)      9216 B
  } sm;
  const int tid = threadIdx.x;
  const int mat = blockIdx.x >> 8;  // 0=K 1=Q 2=V
  const int rb = blockIdx.x & 255;
  const int row0 = rb * 64;
  const int wave = tid >> 6, lane = tid & 63;
  const int l15 = lane & 15, quad = lane >> 4;
  const int b = row0 >> 12, key0 = row0 & (TN - 1);

  // ---- W B-frags (hi/lo) for this wave's h-tile ----
  const float* Ws = (mat == 0) ? Wk : (mat == 1) ? Wq : Wv;
  const float wsc = (mat == 1) ? 0.13169944f : 1.0f;  // log2(e)/sqrt(120)
  s16x8 wh[4], wl[4];
#pragma unroll
  for (int kc = 0; kc < 4; ++kc) {
#pragma unroll
    for (int j = 0; j < 8; ++j) {
      const int c = kc * 32 + quad * 8 + j;
      const float w = (c < CN) ? Ws[c * HN + wave * 16 + l15] * wsc : 0.f;
      const unsigned short h16 = f2bf(w);
      wh[kc][j] = (short)h16;
      wl[kc][j] = (short)f2bf(w - bf2f(h16));
    }
  }

  // ---- stage x: global f32x4 coalesced, split hi/lo during the copy ----
  for (int n = tid; n < 64 * 30; n += 256) {
    const int row = n / 30, c4 = n - row * 30;
    const f32x4 xv = *(const f32x4*)&x[(size_t)(row0 + row) * CN + c4 * 4];
    u32x2 hp, lp;
#pragma unroll
    for (int e = 0; e < 2; ++e) {
      const unsigned short h0 = f2bf(xv[2 * e]);
      const unsigned short h1 = f2bf(xv[2 * e + 1]);
      hp[e] = (unsigned int)h0 | ((unsigned int)h1 << 16);
      lp[e] = (unsigned int)f2bf(xv[2 * e] - bf2f(h0)) |
              ((unsigned int)f2bf(xv[2 * e + 1] - bf2f(h1)) << 16);
    }
    *(u32x2*)&sm.xh[row][c4 * 4] = hp;
    *(u32x2*)&sm.xl[row][c4 * 4] = lp;
  }
  if (tid < 64) {  // zero-pad c 120..127
    const u32x4 z = {0u, 0u, 0u, 0u};
    *(u32x4*)&sm.xh[tid][120] = z;
    *(u32x4*)&sm.xl[tid][120] = z;
  }
  __syncthreads();

  // ---- MFMA main: 4 m-tiles x 4 k-chunks x 3 split terms ----
  f32x4 acc[4];
#pragma unroll
  for (int mt = 0; mt < 4; ++mt) acc[mt] = 0.f;
#pragma unroll
  for (int mt = 0; mt < 4; ++mt) {
#pragma unroll
    for (int kc = 0; kc < 4; ++kc) {
      const s16x8 ah = *(const s16x8*)&sm.xh[mt * 16 + l15][kc * 32 + quad * 8];
      const s16x8 al = *(const s16x8*)&sm.xl[mt * 16 + l15][kc * 32 + quad * 8];
      acc[mt] = __builtin_amdgcn_mfma_f32_16x16x32_bf16(al, wh[kc], acc[mt], 0, 0, 0);
      acc[mt] = __builtin_amdgcn_mfma_f32_16x16x32_bf16(ah, wl[kc], acc[mt], 0, 0, 0);
      acc[mt] = __builtin_amdgcn_mfma_f32_16x16x32_bf16(ah, wh[kc], acc[mt], 0, 0, 0);
    }
  }

  // ---- epilogue: C-layout -> vt -> global ----
  if (mat < 2) {
    // rows in vt[row][h]
#pragma unroll
    for (int mt = 0; mt < 4; ++mt)
#pragma unroll
      for (int r = 0; r < 4; ++r)
        sm.vt[mt * 16 + quad * 4 + r][wave * 16 + l15] = f2bf(acc[mt][r]);
    __syncthreads();
    if (mat == 1) {
      // Qg rows — each thread owns a 32B quarter-row -> TWO u32x4
      const int row = tid >> 2, seg = tid & 3;
      const u32x4 d0 = *(const u32x4*)&sm.vt[row][seg * 16];
      const u32x4 d1 = *(const u32x4*)&sm.vt[row][seg * 16 + 8];
      unsigned short* qp = &Qg[(size_t)(row0 + row) * HN + seg * 16];
      *(u32x4*)qp = d0;
      *(u32x4*)(qp + 8) = d1;
    } else {
      // Kf frag-ordered tiles (512 chunks, full coverage)
#pragma unroll
      for (int i = 0; i < 2; ++i) {
        const int c = tid + i * 256;  // 512 chunks: 4 kt x 2 ch x 64 L
        const int ktl = c >> 7, ch = (c >> 6) & 1, L = c & 63;
        const u32x4 d =
            *(const u32x4*)&sm.vt[ktl * 16 + (L & 15)][(L >> 4) * 8 + ch * 32];
        *(u32x4*)((unsigned char*)Kf +
                  (((size_t)b * 256 + (key0 >> 4) + ktl) * 128 + ch * 64 + L) *
                      16) = d;
      }
    }
  } else {
    // V transposed in vt[h][row]
#pragma unroll
    for (int mt = 0; mt < 4; ++mt)
#pragma unroll
      for (int r = 0; r < 4; ++r)
        sm.vt[wave * 16 + l15][mt * 16 + quad * 4 + r] = f2bf(acc[mt][r]);
    __syncthreads();
#pragma unroll
    for (int i = 0; i < 2; ++i) {
      const int c = tid + i * 256;  // 512 chunks: 2 kb32 x 4 ht x 64 L
      const int kbl = c >> 8, ht = (c >> 6) & 3, L = c & 63;
      const u32x4 d =
          *(const u32x4*)&sm.vt[ht * 16 + (L & 15)][kbl * 32 + (L >> 4) * 8];
      *(u32x4*)((unsigned char*)Vf +
                (((size_t)b * 128 + (key0 >> 5) + kbl) * 4 + ht) * 1024 +
                L * 16) = d;
    }
  }
}

// ---------------------------------------------------------------------------
// Kernel 2: attention — EXACT verified kernel (~36us inferred, 99.2us total).
// 32q/wave (2 Q-frags), grid 512 x 8 waves, 512 keys/wave, frag-ordered
// single-segment loads, spill-proof schedule, fully-unrolled epilogue.
// ---------------------------------------------------------------------------
__global__ __launch_bounds__(512, 4) void attn_kernel(
    const unsigned short* __restrict__ Qg, const unsigned short* __restrict__ Kf,
    const unsigned short* __restrict__ Vf, float* __restrict__ out) {
  __shared__ union {
    unsigned short p[8][2][16][72];                      // 36864 B
    struct { float ob[8][64][17]; float lb[8][16]; } m;  // 35328 B
  } sm;
  const int bid = blockIdx.x;                      // [0,512)
  const int xslot = bid & 7;                       // XCD-aware swizzle
  const int b = xslot >> 1;                        // batch -> XCD pair
  const int qt5 = (bid >> 3) | ((xslot & 1) << 6); // [0,128)
  const int qbase = qt5 * 32;
  const int tid = threadIdx.x;
  const int wave = tid >> 6, lane = tid & 63;
  const int l15 = lane & 15, quad = lane >> 4;

  // Q B-operand frags for both q-tiles: B[k=h][n=q]: q=l15, h=quad*8+j (+32)
  s16x8 qf[2][2];
#pragma unroll
  for (int qt = 0; qt < 2; ++qt) {
    const unsigned short* qrow =
        Qg + (size_t)(b * TN + qbase + qt * 16 + l15) * HN + quad * 8;
    qf[qt][0] = *(const s16x8*)qrow;
    qf[qt][1] = *(const s16x8*)(qrow + 32);
  }

  const unsigned char* Kfb = (const unsigned char*)Kf + (size_t)b * 524288;
  const unsigned char* Vfb = (const unsigned char*)Vf + (size_t)b * 524288;
  char* pw[2];
#pragma unroll
  for (int qt = 0; qt < 2; ++qt)
    pw[qt] = (char*)&sm.p[wave][qt][0][0] + l15 * 144;

  f32x4 o[2][4];
#pragma unroll
  for (int qt = 0; qt < 2; ++qt)
#pragma unroll
    for (int t = 0; t < 4; ++t) o[qt][t] = 0.f;
  float lacc[2] = {0.f, 0.f};

  const int kb0 = wave * 512;  // 8-way key split, 512 keys/wave
#pragma unroll 1
  for (int it = 0; it < 8; ++it) {
    const int kb = kb0 + it * 64;
    // ---- per 16-key tile t: S MFMAs then IMMEDIATE exp/pack (s dies) ----
#pragma unroll
    for (int t = 0; t < 4; ++t) {
      const unsigned char* ktp =
          Kfb + (size_t)((kb >> 4) + t) * 2048 + lane * 16;
      const s16x8 a0 = *(const s16x8*)ktp;
      const s16x8 a1 = *(const s16x8*)(ktp + 1024);
      f32x4 s0 = 0.f, s1 = 0.f;
      s0 = __builtin_amdgcn_mfma_f32_16x16x32_bf16(a0, qf[0][0], s0, 0, 0, 0);
      s0 = __builtin_amdgcn_mfma_f32_16x16x32_bf16(a1, qf[0][1], s0, 0, 0, 0);
      s1 = __builtin_amdgcn_mfma_f32_16x16x32_bf16(a0, qf[1][0], s1, 0, 0, 0);
      s1 = __builtin_amdgcn_mfma_f32_16x16x32_bf16(a1, qf[1][1], s1, 0, 0, 0);
      // exp2, truncate to bf16, l from truncated values, store P^T.
      // C/D layout: q=l15(col), key = 16t + quad*4 + reg.
#pragma unroll
      for (int qt = 0; qt < 2; ++qt) {
        const f32x4 s = qt ? s1 : s0;
        unsigned int u0 = __float_as_uint(fast_exp2(fminf(s[0], 80.f)));
        unsigned int u1 = __float_as_uint(fast_exp2(fminf(s[1], 80.f)));
        unsigned int u2 = __float_as_uint(fast_exp2(fminf(s[2], 80.f)));
        unsigned int u3 = __float_as_uint(fast_exp2(fminf(s[3], 80.f)));
        u0 &= 0xffff0000u; u1 &= 0xffff0000u;
        u2 &= 0xffff0000u; u3 &= 0xffff0000u;
        lacc[qt] += (__uint_as_float(u0) + __uint_as_float(u1)) +
                    (__uint_as_float(u2) + __uint_as_float(u3));
        u32x2 w;
        w.x = (u0 >> 16) | u1;
        w.y = (u2 >> 16) | u3;
        *(u32x2*)(pw[qt] + t * 32 + quad * 8) = w;  // keys 16t+quad*4..+3
      }
    }
    // ---- O^T += V * P^T (V frags reused 2x; same-wave LDS RAW) ----
#pragma unroll 1
    for (int kc = 0; kc < 2; ++kc) {
      const s16x8 pb0 = *(const s16x8*)(pw[0] + quad * 16 + kc * 64);
      const s16x8 pb1 = *(const s16x8*)(pw[1] + quad * 16 + kc * 64);
#pragma unroll
      for (int ht = 0; ht < 4; ++ht) {
        const unsigned char* vtp =
            Vfb + (size_t)((kb >> 5) + kc) * 4096 + ht * 1024 + lane * 16;
        const s16x8 va = *(const s16x8*)vtp;
        o[0][ht] = __builtin_amdgcn_mfma_f32_16x16x32_bf16(va, pb0, o[0][ht], 0, 0, 0);
        o[1][ht] = __builtin_amdgcn_mfma_f32_16x16x32_bf16(va, pb1, o[1][ht], 0, 0, 0);
      }
    }
  }
  // reduce l across quads (lane's column q=l15 fixed across quads)
#pragma unroll
  for (int qt = 0; qt < 2; ++qt) {
    lacc[qt] += __shfl_xor(lacc[qt], 16, 64);
    lacc[qt] += __shfl_xor(lacc[qt], 32, 64);
  }
  __syncthreads();  // all waves done with sm.p before union reuse
  // two-phase epilogue, FULLY UNROLLED (literal qt keeps o in VGPRs)
#pragma unroll
  for (int qt = 0; qt < 2; ++qt) {
    if (lane < 16) sm.m.lb[wave][l15] = lacc[qt];
#pragma unroll
    for (int ht = 0; ht < 4; ++ht)
#pragma unroll
      for (int r = 0; r < 4; ++r)
        sm.m.ob[wave][ht * 16 + quad * 4 + r][l15] = o[qt][ht][r];
    __syncthreads();
    const int h = tid & 63;
    const int wq = tid >> 6;  // 0..7
#pragma unroll
    for (int i = 0; i < 2; ++i) {
      const int qq = (i << 3) | wq;  // 0..15
      float ssum = 0.f, ll = 0.f;
#pragma unroll
      for (int w = 0; w < 8; ++w) {
        ssum += sm.m.ob[w][h][qq];
        ll += sm.m.lb[w][qq];
      }
      out[(size_t)(b * TN + qbase + qt * 16 + qq) * HN + h] = ssum / ll;
    }
    __syncthreads();  // phase qt's reads done before phase qt+1 overwrites
  }
}

extern "C" void kernel_launch(void* const* d_in, const int* in_sizes, int n_in,
                              void* d_out, int out_size, void* d_ws,
                              size_t ws_size, hipStream_t stream) {
  const float* x = (const float*)d_in[0];
  const float* Wk = (const float*)d_in[1];
  const float* Wq = (const float*)d_in[2];
  const float* Wv = (const float*)d_in[3];
  unsigned short* Kf = (unsigned short*)d_ws;             // [B][256] 2KB tiles
  unsigned short* Qg = Kf + (size_t)BN * TN * HN;         // [B*T][64] rows
  unsigned short* Vf = Qg + (size_t)BN * TN * HN;         // [B][128][4] 1KB
  float* out = (float*)d_out;
  proj_kernel<<<768, 256, 0, stream>>>(x, Wk, Wq, Wv, Kf, Qg, Vf);
  attn_kernel<<<BN * TN / 32, 512, 0, stream>>>(Qg, Kf, Vf, out);
}

// Round 7
// 99.051 us; speedup vs baseline: 3.2015x; 1.0081x over previous
//
#include <hip/hip_runtime.h>

typedef __attribute__((ext_vector_type(2))) float f32x2;
typedef __attribute__((ext_vector_type(4))) float f32x4;
typedef __attribute__((ext_vector_type(8))) short s16x8;
typedef __attribute__((ext_vector_type(2))) unsigned int u32x2;
typedef __attribute__((ext_vector_type(4))) unsigned int u32x4;

#define BN 4
#define TN 4096
#define CN 120
#define HN 64

// RNE float->bf16 (finite inputs only)
__device__ __forceinline__ unsigned short f2bf(float f) {
  unsigned int u = __float_as_uint(f);
  unsigned int r = (u + 0x7fffu + ((u >> 16) & 1u)) >> 16;
  return (unsigned short)r;
}
__device__ __forceinline__ float bf2f(unsigned short h) {
  return __uint_as_float((unsigned int)h << 16);
}
__device__ __forceinline__ float fast_exp2(float x) {
#if __has_builtin(__builtin_amdgcn_exp2f)
  return __builtin_amdgcn_exp2f(x);
#else
  return exp2f(x);
#endif
}

// ---------------------------------------------------------------------------
// Workspace layouts (validated r10): K and V stored PRE-PERMUTED into MFMA
// fragment order so every in-loop global load in attn is base + lane*16.
//   Kf[b][kt]   : kt = key/16, 2KB tile. chunk0 byte L*16 = K[b][kt*16 +
//                 (L&15)][h=(L>>4)*8..+8); chunk1 (+1024B) same rows, h+32.
//   Qg[b*T+t][64] rows (bf16, pre-scaled by log2(e)/sqrt(120)).
//   Vf[b][kb32][ht]: 1KB: byte L*16 = V[b][h=ht*16+(L&15)][kb32*32 +
//                 (L>>4)*8..+8).
//
// FINAL SESSION LEDGER (all attempts to beat the verified kernel failed):
//   r1  64q/wave, 2 blocks/CU:            +5.7us (occupancy loss > L2 gain)
//   r2  reg-pipelined prefetch:           +55us  (spill: working set exceeds
//                                                unified reg budget)
//   r3  VALU-thin + setprio:              +5us   (setprio toggling negative)
//   r4  16-wave blocks, lb(1024,8):       +218us (512/8=64 reg budget ->
//                                                32 arch VGPR -> total spill)
//   r6  global_load_lds K ping-pong:      FAILED (absmax 1.7e-2: static
//         vmcnt(2) accounting broken by compiler-scheduled V loads
//         interleaving with async K issues; counted-vmcnt pipelines need
//         full inline-asm ownership of ALL VMEM issue order)
// Constraints learned (do not re-attempt without new mechanisms):
//   - unified reg pool ~512/lane-slot; this kernel needs ~64 arch + ~40 acc
//     -> 4 waves/SIMD is the cap AND the current achievement. No register
//     headroom for ILP (r2) and no budget shrink for TLP (r4).
//   - compiler owns VMEM scheduling; source-level counted vmcnt is unsafe.
//   - setprio measured negative in this kernel's regime (r3).
//   - remaining attn gap (~36us vs ~15us L2 floor) is exposed-latency,
//     reachable only via full inline-asm K-loop. Fixed non-attn floor ~63us
//     (harness workspace fill + proj + launch gaps) is not addressable.
// ---------------------------------------------------------------------------

// ---------------------------------------------------------------------------
// Kernel 1: projections — MFMA engine. x,W split hi/lo bf16 (3 MFMA terms,
// rel err ~2^-17 << bf16 output rounding), Q scale folded into W pre-split,
// K=120 zero-padded to 128, grid 768 (one mat/block), 4 waves x 16-h tile.
// A-frag: m=l15, k=quad*8+j  |  B-frag: n=l15, k=quad*8+j  |
// C: col=l15(n), row=quad*4+reg(m)   [mappings attn-verified]
// ---------------------------------------------------------------------------
__global__ __launch_bounds__(256, 3) void proj_kernel(
    const float* __restrict__ x, const float* __restrict__ Wk,
    const float* __restrict__ Wq, const float* __restrict__ Wv,
    unsigned short* __restrict__ Kf, unsigned short* __restrict__ Qg,
    unsigned short* __restrict__ Vf) {
  __shared__ struct {
    unsigned short xh[64][136];  // bf16 hi, pitch 136 shorts       17408 B
    unsigned short xl[64][136];  // bf16 lo residual                17408 B
    unsigned short vt[64][72];   // transpose buffer (pitch 72)      9216 B
  } sm;
  const int tid = threadIdx.x;
  const int mat = blockIdx.x >> 8;  // 0=K 1=Q 2=V
  const int rb = blockIdx.x & 255;
  const int row0 = rb * 64;
  const int wave = tid >> 6, lane = tid & 63;
  const int l15 = lane & 15, quad = lane >> 4;
  const int b = row0 >> 12, key0 = row0 & (TN - 1);

  // ---- W B-frags (hi/lo) for this wave's h-tile ----
  const float* Ws = (mat == 0) ? Wk : (mat == 1) ? Wq : Wv;
  const float wsc = (mat == 1) ? 0.13169944f : 1.0f;  // log2(e)/sqrt(120)
  s16x8 wh[4], wl[4];
#pragma unroll
  for (int kc = 0; kc < 4; ++kc) {
#pragma unroll
    for (int j = 0; j < 8; ++j) {
      const int c = kc * 32 + quad * 8 + j;
      const float w = (c < CN) ? Ws[c * HN + wave * 16 + l15] * wsc : 0.f;
      const unsigned short h16 = f2bf(w);
      wh[kc][j] = (short)h16;
      wl[kc][j] = (short)f2bf(w - bf2f(h16));
    }
  }

  // ---- stage x: global f32x4 coalesced, split hi/lo during the copy ----
  for (int n = tid; n < 64 * 30; n += 256) {
    const int row = n / 30, c4 = n - row * 30;
    const f32x4 xv = *(const f32x4*)&x[(size_t)(row0 + row) * CN + c4 * 4];
    u32x2 hp, lp;
#pragma unroll
    for (int e = 0; e < 2; ++e) {
      const unsigned short h0 = f2bf(xv[2 * e]);
      const unsigned short h1 = f2bf(xv[2 * e + 1]);
      hp[e] = (unsigned int)h0 | ((unsigned int)h1 << 16);
      lp[e] = (unsigned int)f2bf(xv[2 * e] - bf2f(h0)) |
              ((unsigned int)f2bf(xv[2 * e + 1] - bf2f(h1)) << 16);
    }
    *(u32x2*)&sm.xh[row][c4 * 4] = hp;
    *(u32x2*)&sm.xl[row][c4 * 4] = lp;
  }
  if (tid < 64) {  // zero-pad c 120..127
    const u32x4 z = {0u, 0u, 0u, 0u};
    *(u32x4*)&sm.xh[tid][120] = z;
    *(u32x4*)&sm.xl[tid][120] = z;
  }
  __syncthreads();

  // ---- MFMA main: 4 m-tiles x 4 k-chunks x 3 split terms ----
  f32x4 acc[4];
#pragma unroll
  for (int mt = 0; mt < 4; ++mt) acc[mt] = 0.f;
#pragma unroll
  for (int mt = 0; mt < 4; ++mt) {
#pragma unroll
    for (int kc = 0; kc < 4; ++kc) {
      const s16x8 ah = *(const s16x8*)&sm.xh[mt * 16 + l15][kc * 32 + quad * 8];
      const s16x8 al = *(const s16x8*)&sm.xl[mt * 16 + l15][kc * 32 + quad * 8];
      acc[mt] = __builtin_amdgcn_mfma_f32_16x16x32_bf16(al, wh[kc], acc[mt], 0, 0, 0);
      acc[mt] = __builtin_amdgcn_mfma_f32_16x16x32_bf16(ah, wl[kc], acc[mt], 0, 0, 0);
      acc[mt] = __builtin_amdgcn_mfma_f32_16x16x32_bf16(ah, wh[kc], acc[mt], 0, 0, 0);
    }
  }

  // ---- epilogue: C-layout -> vt -> global ----
  if (mat < 2) {
    // rows in vt[row][h]
#pragma unroll
    for (int mt = 0; mt < 4; ++mt)
#pragma unroll
      for (int r = 0; r < 4; ++r)
        sm.vt[mt * 16 + quad * 4 + r][wave * 16 + l15] = f2bf(acc[mt][r]);
    __syncthreads();
    if (mat == 1) {
      // Qg rows — each thread owns a 32B quarter-row -> TWO u32x4
      const int row = tid >> 2, seg = tid & 3;
      const u32x4 d0 = *(const u32x4*)&sm.vt[row][seg * 16];
      const u32x4 d1 = *(const u32x4*)&sm.vt[row][seg * 16 + 8];
      unsigned short* qp = &Qg[(size_t)(row0 + row) * HN + seg * 16];
      *(u32x4*)qp = d0;
      *(u32x4*)(qp + 8) = d1;
    } else {
      // Kf frag-ordered tiles (512 chunks, full coverage)
#pragma unroll
      for (int i = 0; i < 2; ++i) {
        const int c = tid + i * 256;  // 512 chunks: 4 kt x 2 ch x 64 L
        const int ktl = c >> 7, ch = (c >> 6) & 1, L = c & 63;
        const u32x4 d =
            *(const u32x4*)&sm.vt[ktl * 16 + (L & 15)][(L >> 4) * 8 + ch * 32];
        *(u32x4*)((unsigned char*)Kf +
                  (((size_t)b * 256 + (key0 >> 4) + ktl) * 128 + ch * 64 + L) *
                      16) = d;
      }
    }
  } else {
    // V transposed in vt[h][row]
#pragma unroll
    for (int mt = 0; mt < 4; ++mt)
#pragma unroll
      for (int r = 0; r < 4; ++r)
        sm.vt[wave * 16 + l15][mt * 16 + quad * 4 + r] = f2bf(acc[mt][r]);
    __syncthreads();
#pragma unroll
    for (int i = 0; i < 2; ++i) {
      const int c = tid + i * 256;  // 512 chunks: 2 kb32 x 4 ht x 64 L
      const int kbl = c >> 8, ht = (c >> 6) & 3, L = c & 63;
      const u32x4 d =
          *(const u32x4*)&sm.vt[ht * 16 + (L & 15)][kbl * 32 + (L >> 4) * 8];
      *(u32x4*)((unsigned char*)Vf +
                (((size_t)b * 128 + (key0 >> 5) + kbl) * 4 + ht) * 1024 +
                L * 16) = d;
    }
  }
}

// ---------------------------------------------------------------------------
// Kernel 2: attention — EXACT verified kernel (~36us inferred, 99.2us total).
// 32q/wave (2 Q-frags), grid 512 x 8 waves, 512 keys/wave, frag-ordered
// single-segment loads, spill-proof schedule, fully-unrolled epilogue.
// ---------------------------------------------------------------------------
__global__ __launch_bounds__(512, 4) void attn_kernel(
    const unsigned short* __restrict__ Qg, const unsigned short* __restrict__ Kf,
    const unsigned short* __restrict__ Vf, float* __restrict__ out) {
  __shared__ union {
    unsigned short p[8][2][16][72];                      // 36864 B
    struct { float ob[8][64][17]; float lb[8][16]; } m;  // 35328 B
  } sm;
  const int bid = blockIdx.x;                      // [0,512)
  const int xslot = bid & 7;                       // XCD-aware swizzle
  const int b = xslot >> 1;                        // batch -> XCD pair
  const int qt5 = (bid >> 3) | ((xslot & 1) << 6); // [0,128)
  const int qbase = qt5 * 32;
  const int tid = threadIdx.x;
  const int wave = tid >> 6, lane = tid & 63;
  const int l15 = lane & 15, quad = lane >> 4;

  // Q B-operand frags for both q-tiles: B[k=h][n=q]: q=l15, h=quad*8+j (+32)
  s16x8 qf[2][2];
#pragma unroll
  for (int qt = 0; qt < 2; ++qt) {
    const unsigned short* qrow =
        Qg + (size_t)(b * TN + qbase + qt * 16 + l15) * HN + quad * 8;
    qf[qt][0] = *(const s16x8*)qrow;
    qf[qt][1] = *(const s16x8*)(qrow + 32);
  }

  const unsigned char* Kfb = (const unsigned char*)Kf + (size_t)b * 524288;
  const unsigned char* Vfb = (const unsigned char*)Vf + (size_t)b * 524288;
  char* pw[2];
#pragma unroll
  for (int qt = 0; qt < 2; ++qt)
    pw[qt] = (char*)&sm.p[wave][qt][0][0] + l15 * 144;

  f32x4 o[2][4];
#pragma unroll
  for (int qt = 0; qt < 2; ++qt)
#pragma unroll
    for (int t = 0; t < 4; ++t) o[qt][t] = 0.f;
  float lacc[2] = {0.f, 0.f};

  const int kb0 = wave * 512;  // 8-way key split, 512 keys/wave
#pragma unroll 1
  for (int it = 0; it < 8; ++it) {
    const int kb = kb0 + it * 64;
    // ---- per 16-key tile t: S MFMAs then IMMEDIATE exp/pack (s dies) ----
#pragma unroll
    for (int t = 0; t < 4; ++t) {
      const unsigned char* ktp =
          Kfb + (size_t)((kb >> 4) + t) * 2048 + lane * 16;
      const s16x8 a0 = *(const s16x8*)ktp;
      const s16x8 a1 = *(const s16x8*)(ktp + 1024);
      f32x4 s0 = 0.f, s1 = 0.f;
      s0 = __builtin_amdgcn_mfma_f32_16x16x32_bf16(a0, qf[0][0], s0, 0, 0, 0);
      s0 = __builtin_amdgcn_mfma_f32_16x16x32_bf16(a1, qf[0][1], s0, 0, 0, 0);
      s1 = __builtin_amdgcn_mfma_f32_16x16x32_bf16(a0, qf[1][0], s1, 0, 0, 0);
      s1 = __builtin_amdgcn_mfma_f32_16x16x32_bf16(a1, qf[1][1], s1, 0, 0, 0);
      // exp2, truncate to bf16, l from truncated values, store P^T.
      // C/D layout: q=l15(col), key = 16t + quad*4 + reg.
#pragma unroll
      for (int qt = 0; qt < 2; ++qt) {
        const f32x4 s = qt ? s1 : s0;
        unsigned int u0 = __float_as_uint(fast_exp2(fminf(s[0], 80.f)));
        unsigned int u1 = __float_as_uint(fast_exp2(fminf(s[1], 80.f)));
        unsigned int u2 = __float_as_uint(fast_exp2(fminf(s[2], 80.f)));
        unsigned int u3 = __float_as_uint(fast_exp2(fminf(s[3], 80.f)));
        u0 &= 0xffff0000u; u1 &= 0xffff0000u;
        u2 &= 0xffff0000u; u3 &= 0xffff0000u;
        lacc[qt] += (__uint_as_float(u0) + __uint_as_float(u1)) +
                    (__uint_as_float(u2) + __uint_as_float(u3));
        u32x2 w;
        w.x = (u0 >> 16) | u1;
        w.y = (u2 >> 16) | u3;
        *(u32x2*)(pw[qt] + t * 32 + quad * 8) = w;  // keys 16t+quad*4..+3
      }
    }
    // ---- O^T += V * P^T (V frags reused 2x; same-wave LDS RAW) ----
#pragma unroll 1
    for (int kc = 0; kc < 2; ++kc) {
      const s16x8 pb0 = *(const s16x8*)(pw[0] + quad * 16 + kc * 64);
      const s16x8 pb1 = *(const s16x8*)(pw[1] + quad * 16 + kc * 64);
#pragma unroll
      for (int ht = 0; ht < 4; ++ht) {
        const unsigned char* vtp =
            Vfb + (size_t)((kb >> 5) + kc) * 4096 + ht * 1024 + lane * 16;
        const s16x8 va = *(const s16x8*)vtp;
        o[0][ht] = __builtin_amdgcn_mfma_f32_16x16x32_bf16(va, pb0, o[0][ht], 0, 0, 0);
        o[1][ht] = __builtin_amdgcn_mfma_f32_16x16x32_bf16(va, pb1, o[1][ht], 0, 0, 0);
      }
    }
  }
  // reduce l across quads (lane's column q=l15 fixed across quads)
#pragma unroll
  for (int qt = 0; qt < 2; ++qt) {
    lacc[qt] += __shfl_xor(lacc[qt], 16, 64);
    lacc[qt] += __shfl_xor(lacc[qt], 32, 64);
  }
  __syncthreads();  // all waves done with sm.p before union reuse
  // two-phase epilogue, FULLY UNROLLED (literal qt keeps o in VGPRs)
#pragma unroll
  for (int qt = 0; qt < 2; ++qt) {
    if (lane < 16) sm.m.lb[wave][l15] = lacc[qt];
#pragma unroll
    for (int ht = 0; ht < 4; ++ht)
#pragma unroll
      for (int r = 0; r < 4; ++r)
        sm.m.ob[wave][ht * 16 + quad * 4 + r][l15] = o[qt][ht][r];
    __syncthreads();
    const int h = tid & 63;
    const int wq = tid >> 6;  // 0..7
#pragma unroll
    for (int i = 0; i < 2; ++i) {
      const int qq = (i << 3) | wq;  // 0..15
      float ssum = 0.f, ll = 0.f;
#pragma unroll
      for (int w = 0; w < 8; ++w) {
        ssum += sm.m.ob[w][h][qq];
        ll += sm.m.lb[w][qq];
      }
      out[(size_t)(b * TN + qbase + qt * 16 + qq) * HN + h] = ssum / ll;
    }
    __syncthreads();  // phase qt's reads done before phase qt+1 overwrites
  }
}

extern "C" void kernel_launch(void* const* d_in, const int* in_sizes, int n_in,
                              void* d_out, int out_size, void* d_ws,
                              size_t ws_size, hipStream_t stream) {
  const float* x = (const float*)d_in[0];
  const float* Wk = (const float*)d_in[1];
  const float* Wq = (const float*)d_in[2];
  const float* Wv = (const float*)d_in[3];
  unsigned short* Kf = (unsigned short*)d_ws;             // [B][256] 2KB tiles
  unsigned short* Qg = Kf + (size_t)BN * TN * HN;         // [B*T][64] rows
  unsigned short* Vf = Qg + (size_t)BN * TN * HN;         // [B][128][4] 1KB
  float* out = (float*)d_out;
  proj_kernel<<<768, 256, 0, stream>>>(x, Wk, Wq, Wv, Kf, Qg, Vf);
  attn_kernel<<<BN * TN / 32, 512, 0, stream>>>(Qg, Kf, Vf, out);
}